// Round 12
// baseline (197.093 us; speedup 1.0000x reference)
//
#include <hip/hip_runtime.h>
#include <math.h>

// Problem constants (reference file)
#define NPTS   500000
#define CIN    16
#define COUT   64
#define GRID_W 256
#define NCELL  65536
#define BCAP   32                        // bucket capacity (P(overflow) ~ 5e-7)

// ws layout (bytes)
#define WS_HIST   0                      // 65536 u32 (256 KB)
#define WS_BUCKET 262144                 // 65536*32 u32 point-id buckets (8 MB)
#define WS_FEAT   8650752                // 500000*64 f16 feature rows (64 MB)
#define WS_NEED   (WS_FEAT + (size_t)NPTS * COUT * 2)

#define MB_BLOCKS ((NPTS + 511) / 512)   // 977  (main kernel, 512 thr)

#define W_HALFS   18432                  // (28+8) frags * 64 lanes * 8 halfs
#define W1_FRAGS  28                     // 7 k-steps * 4 ch-tiles

typedef _Float16 f16x8 __attribute__((ext_vector_type(8)));
typedef _Float16 f16x2 __attribute__((ext_vector_type(2)));
typedef float    f32x4 __attribute__((ext_vector_type(4)));

__device__ __forceinline__ f16x2 pk2(float a, float b) {
    auto r = __builtin_amdgcn_cvt_pkrtz(a, b);   // v_cvt_pkrtz_f16_f32
    union { decltype(r) x; f16x2 y; } u; u.x = r;
    return u.y;
}

// raw v_sin_f32: input in REVOLUTIONS (|x| < 1 here, no range reduction needed)
__device__ __forceinline__ float vsin(float x) {
    float r;
    asm("v_sin_f32 %0, %1" : "=v"(r) : "v"(x));
    return r;
}

// raw v_exp_f32: 2^x
__device__ __forceinline__ float vexp2(float x) {
    float r;
    asm("v_exp_f32 %0, %1" : "=v"(r) : "v"(x));
    return r;
}

__device__ __forceinline__ int cell_index(float v) {
    float nf = fminf(fmaxf((v + 1.0f) * 0.5f, 0.0f), 1.0f);
    int i = (int)floorf(nf * 256.0f);
    return i > 255 ? 255 : i;
}

__device__ __forceinline__ int flat_of(const float* pos, int p, int a1, int a2) {
    float pa1 = pos[p * 3 + a1];
    float pa2 = pos[p * 3 + a2];
    return cell_index(pa1) * GRID_W + cell_index(pa2);
}

// K0: MFMA MLP (R5 body) + INLINE weight pack (W1/W2 are L2-resident; 70 KB
// per block, ~2us aggregate — removes the pack kernel node and its serial
// dependency) + R9 epilogue rank assignment into fixed-capacity buckets.
__global__ __launch_bounds__(512, 4)
void mlp_mfma_kernel(const float* __restrict__ pos,
                     const float* __restrict__ feats,
                     const float* __restrict__ W1,
                     const float* __restrict__ W2,
                     const float* __restrict__ b1,
                     const float* __restrict__ ln_g,
                     const float* __restrict__ ln_b,
                     const int*   __restrict__ ax1p,
                     const int*   __restrict__ ax2p,
                     unsigned int* __restrict__ hist,
                     int* __restrict__ bucket,
                     _Float16* __restrict__ featbuf,
                     float* __restrict__ out,
                     int use_feat)
{
    __shared__ __align__(16) _Float16 WF[W_HALFS];   // 36864 B
    __shared__ __align__(16) _Float16 PS[8 * 1024];  // 16384 B (2 KB per wave)

    // inline frag-order weight pack (same indexing as the old pack kernel)
    for (int i = threadIdx.x; i < W_HALFS; i += 512) {
        int j = i & 7, ln = (i >> 3) & 63, f = i >> 9;
        int k  = ((f < W1_FRAGS) ? (f >> 2) : ((f - W1_FRAGS) >> 2)) * 32 + ((ln >> 4) << 3) + j;
        int ch = (f & 3) * 16 + (ln & 15);
        float v;
        if (f < W1_FRAGS) v = (k < 208) ? W1[k * 64 + ch] : 0.0f;
        else              v = W2[k * 64 + ch];
        WF[i] = (_Float16)v;
    }

    const int lane = threadIdx.x & 63;
    const int wv   = threadIdx.x >> 6;
    const int g    = lane >> 4;        // quad
    const int n    = lane & 15;        // point-within-tile (B-col / D-col)
    char* Pw = (char*)(PS + wv * 1024);            // 2048 B per wave
    const unsigned sw = (unsigned)((n & 7) << 4);  // XOR swizzle (byte, 16B unit)

    const int wbase = blockIdx.x * 512 + wv * 64;
    const int a1 = ax1p[0], a2 = ax2p[0];

    // lane-constant PE base frequency IN REVOLUTIONS: 0.25 * 2^(f0/32)
    const float base  = 0.25f * exp2f((float)((8 * g + 16) & 31) * 0.03125f);
    const float RSTEP = 1.02189714865411668f;    // 2^(1/32)

    __syncthreads();   // WF visible

    #pragma unroll 1
    for (int tp = 0; tp < 2; ++tp) {
        // ---- load 2 tiles' point data -------------------------------------
        float px[2], py[2], pz[2];
        f16x8 fH[2];
        #pragma unroll
        for (int u = 0; u < 2; ++u) {
            const int st = wbase + (tp * 2 + u) * 16 + n;
            const int p  = (st < NPTS) ? st : 0;
            px[u] = pos[3 * p + 0];
            py[u] = pos[3 * p + 1];
            pz[u] = pos[3 * p + 2];
            if (g < 2) {
                const float4* fr = (const float4*)(feats + (size_t)p * CIN + g * 8);
                float4 fa = fr[0], fb = fr[1];
                union { f16x8 v; f16x2 h[4]; } Uf;
                Uf.h[0] = pk2(fa.x, fa.y); Uf.h[1] = pk2(fa.z, fa.w);
                Uf.h[2] = pk2(fb.x, fb.y); Uf.h[3] = pk2(fb.z, fb.w);
                fH[u] = Uf.v;
            }
        }

        // ---- GEMM1: acc[u][c] = H[ch 16c+4g+r][point n], K = 224 ----------
        f32x4 acc[2][4];
        #pragma unroll
        for (int u = 0; u < 2; ++u)
            #pragma unroll
            for (int c = 0; c < 4; ++c)
                acc[u][c] = (f32x4){0.0f, 0.0f, 0.0f, 0.0f};

        #pragma unroll
        for (int s = 0; s < 7; ++s) {
            f16x8 U[2];
            const int k0 = s * 32 + g * 8;
            if (s == 0 && g < 2) {               // feats (pre-packed)
                U[0] = fH[0]; U[1] = fH[1];
            } else if (k0 >= 208) {              // zero pad (s==6, g>=2)
                union { f16x8 v; f16x2 h[4]; } Z;
                #pragma unroll
                for (int q = 0; q < 4; ++q) Z.h[q] = pk2(0.0f, 0.0f);
                U[0] = Z.v; U[1] = Z.v;
            } else {                             // PE: v_sin in revolutions
                const int   e    = k0 - 16;
                const float off  = (e & 32) ? 0.25f : 0.0f;
                const float offc = (e & 32) ? (0.25f * (1.0f - RSTEP)) : 0.0f;
                #pragma unroll
                for (int u = 0; u < 2; ++u) {
                    const float pv = (e < 64) ? px[u] : ((e < 128) ? py[u] : pz[u]);
                    float a = fmaf(pv, base, off);
                    union { f16x8 v; f16x2 h[4]; } G;
                    #pragma unroll
                    for (int q = 0; q < 4; ++q) {
                        float v0 = vsin(a); a = fmaf(a, RSTEP, offc);
                        float v1 = vsin(a); a = fmaf(a, RSTEP, offc);
                        G.h[q] = pk2(v0, v1);
                    }
                    U[u] = G.v;
                }
            }
            #pragma unroll
            for (int c = 0; c < 4; ++c) {
                f16x8 af = ((const f16x8*)WF)[(s * 4 + c) * 64 + lane];
                acc[0][c] = __builtin_amdgcn_mfma_f32_16x16x32_f16(af, U[0], acc[0][c], 0, 0, 0);
                acc[1][c] = __builtin_amdgcn_mfma_f32_16x16x32_f16(af, U[1], acc[1][c], 0, 0, 0);
            }
        }

        // ---- per tile: LN + GELU -> Pw, GEMM2, dense store ----------------
        #pragma unroll
        for (int u = 0; u < 2; ++u) {
            // LN stats (lane-local 16 + 2 shuffles)
            float s1 = 0.0f, s2 = 0.0f;
            #pragma unroll
            for (int c = 0; c < 4; ++c) {
                f32x4 b1q = *(const f32x4*)(b1 + 16 * c + 4 * g);
                #pragma unroll
                for (int r = 0; r < 4; ++r) {
                    float x = acc[u][c][r] + b1q[r];
                    acc[u][c][r] = x;
                    s1 += x; s2 += x * x;
                }
            }
            s1 += __shfl_xor(s1, 16); s2 += __shfl_xor(s2, 16);
            s1 += __shfl_xor(s1, 32); s2 += __shfl_xor(s2, 32);
            const float mu   = s1 * (1.0f / 64.0f);
            const float var  = s2 * (1.0f / 64.0f) - mu * mu;
            const float rstd = __builtin_amdgcn_rsqf(var + 1e-5f);

            // GELU via x*sigmoid(2u); exp folded to base-2: 2u*log2e in poly
            #pragma unroll
            for (int c = 0; c < 4; ++c) {
                f32x4 gq = *(const f32x4*)(ln_g + 16 * c + 4 * g);
                f32x4 bq = *(const f32x4*)(ln_b + 16 * c + 4 * g);
                float gv[4];
                #pragma unroll
                for (int r = 0; r < 4; ++r) {
                    float x  = (acc[u][c][r] - mu) * rstd * gq[r] + bq[r];
                    // 2*log2(e)*0.79788456 = 2.30211812 ; 2*log2(e)*0.03567741 = 0.10295203
                    float w  = x * (2.30211812f + 0.10295203f * x * x);
                    float e2 = vexp2(w);
                    gv[r] = x * e2 * __builtin_amdgcn_rcpf(e2 + 1.0f);
                }
                union { f16x2 h[2]; uint2 u2; } W;
                W.h[0] = pk2(gv[0], gv[1]);
                W.h[1] = pk2(gv[2], gv[3]);
                *(uint2*)(Pw + n * 128 + (((unsigned)(32 * c + 8 * g)) ^ sw)) = W.u2;
            }

            // GEMM2: acc2[c] = O[ch 16c+4g+r][point n]
            f32x4 acc2[4];
            #pragma unroll
            for (int c = 0; c < 4; ++c) acc2[c] = (f32x4){0.0f, 0.0f, 0.0f, 0.0f};
            #pragma unroll
            for (int s = 0; s < 2; ++s) {
                f16x8 bf2 = *(const f16x8*)(Pw + n * 128 + (((unsigned)(64 * s + 16 * g)) ^ sw));
                #pragma unroll
                for (int c = 0; c < 4; ++c) {
                    f16x8 af = ((const f16x8*)WF)[(W1_FRAGS + s * 4 + c) * 64 + lane];
                    acc2[c] = __builtin_amdgcn_mfma_f32_16x16x32_f16(af, bf2, acc2[c], 0, 0, 0);
                }
            }

            if (use_feat) {
                // DENSE row write straight from registers: lane (g,n) owns
                // channels 16c+4g..16c+4g+3 of point (wbase + tile*16 + n).
                const int gs = wbase + (tp * 2 + u) * 16 + n;
                if (gs < NPTS) {
                    _Float16* dstp = featbuf + (size_t)gs * COUT + 4 * g;
                    #pragma unroll
                    for (int c = 0; c < 4; ++c) {
                        union { f16x2 h[2]; uint2 u2; } W;
                        W.h[0] = pk2(acc2[c][0], acc2[c][1]);
                        W.h[1] = pk2(acc2[c][2], acc2[c][3]);
                        *(uint2*)(dstp + 16 * c) = W.u2;
                    }
                }
            } else {
                // fallback: direct fp32 atomics (correctness path, not perf)
                const int st = wbase + (tp * 2 + u) * 16 + n;
                if (st < NPTS) {
                    const int cellr = flat_of(pos, st, a1, a2);
                    #pragma unroll
                    for (int c = 0; c < 4; ++c)
                        #pragma unroll
                        for (int r = 0; r < 4; ++r)
                            unsafeAtomicAdd(&out[(size_t)(16 * c + 4 * g + r) * NCELL + cellr],
                                            acc2[c][r]);
                }
            }
        }

        // ---- rank assignment (R9 epilogue placement) -> direct bucket write.
        // Lane group g==0 handles tile u=0, g==1 handles u=1 (pos in regs).
        {
            const int st2 = wbase + (tp * 2 + (g & 1)) * 16 + n;
            if (g < 2 && st2 < NPTS) {
                const float qx = (g & 1) ? px[1] : px[0];
                const float qy = (g & 1) ? py[1] : py[0];
                const float qz = (g & 1) ? pz[1] : pz[0];
                const float pa1 = (a1 == 0) ? qx : ((a1 == 1) ? qy : qz);
                const float pa2 = (a2 == 0) ? qx : ((a2 == 1) ? qy : qz);
                const int flat = cell_index(pa1) * GRID_W + cell_index(pa2);
                const unsigned int old = atomicAdd(&hist[flat], 1u);
                if (bucket && old < BCAP) bucket[flat * BCAP + (int)old] = st2;
            }
        }
    }
}

// K1: per-cell reduce, 2 cells per wave (doubles gathers in flight; the
// gather is a single L3 round trip for most cells since avg cnt ~ 7.6).
// Block = 512 thr = 8 waves = 16 cells; 4096 blocks.
__global__ __launch_bounds__(512)
void reduce_kernel(const _Float16* __restrict__ featbuf,
                   const int* __restrict__ bucket,
                   const unsigned int* __restrict__ hist,
                   const float* __restrict__ b2,
                   float* __restrict__ out)
{
    __shared__ float R[16][66];
    const int lane  = threadIdx.x & 63;
    const int wvid  = threadIdx.x >> 6;    // 0..7
    const int cbase = blockIdx.x * 16;
    const int cq    = lane & 7;            // channel octet: ch = cq*8 + j
    const int rsl   = lane >> 3;           // row slot 0..7

    const int c0 = cbase + wvid * 2;
    const int c1 = c0 + 1;
    const unsigned int cnt0 = hist[c0], cnt1 = hist[c1];
    const unsigned int cu0 = cnt0 < BCAP ? cnt0 : BCAP;
    const unsigned int cu1 = cnt1 < BCAP ? cnt1 : BCAP;
    const int bb0 = c0 * BCAP, bb1 = c1 * BCAP;

    float a0[8], a1v[8];
    #pragma unroll
    for (int j = 0; j < 8; ++j) { a0[j] = 0.0f; a1v[j] = 0.0f; }

    const unsigned int kmax = cu0 > cu1 ? cu0 : cu1;
    for (unsigned int k = 0; k < kmax; k += 8) {
        const unsigned int kk = k + (unsigned int)rsl;
        const bool ok0 = kk < cu0;
        const bool ok1 = kk < cu1;
        // clamped index keeps reads inside the bucket region; result masked
        int r0 = bucket[bb0 + (int)(ok0 ? kk : 0u)];
        int r1 = bucket[bb1 + (int)(ok1 ? kk : 0u)];
        r0 = ok0 ? r0 : 0;
        r1 = ok1 ? r1 : 0;
        union { uint4 u; f16x2 h[4]; } V0, V1;
        V0.u = *(const uint4*)(featbuf + (size_t)r0 * COUT + cq * 8);
        V1.u = *(const uint4*)(featbuf + (size_t)r1 * COUT + cq * 8);
        #pragma unroll
        for (int j = 0; j < 4; ++j) {
            a0[2 * j]      += ok0 ? (float)V0.h[j].x : 0.0f;
            a0[2 * j + 1]  += ok0 ? (float)V0.h[j].y : 0.0f;
            a1v[2 * j]     += ok1 ? (float)V1.h[j].x : 0.0f;
            a1v[2 * j + 1] += ok1 ? (float)V1.h[j].y : 0.0f;
        }
    }
    #pragma unroll
    for (int m = 8; m <= 32; m <<= 1)
        #pragma unroll
        for (int j = 0; j < 8; ++j) {
            a0[j]  += __shfl_xor(a0[j], m);
            a1v[j] += __shfl_xor(a1v[j], m);
        }

    if (rsl == 0) {
        float4 b2a = *(const float4*)(b2 + cq * 8);
        float4 b2b = *(const float4*)(b2 + cq * 8 + 4);
        const float bb[8] = {b2a.x, b2a.y, b2a.z, b2a.w, b2b.x, b2b.y, b2b.z, b2b.w};
        const float i0 = 1.0f / fmaxf((float)cnt0, 1.0f);
        const float i1 = 1.0f / fmaxf((float)cnt1, 1.0f);
        #pragma unroll
        for (int j = 0; j < 8; ++j) {
            R[wvid * 2 + 0][cq * 8 + j] = cnt0 ? (a0[j]  * i0 + bb[j]) : 0.0f;
            R[wvid * 2 + 1][cq * 8 + j] = cnt1 ? (a1v[j] * i1 + bb[j]) : 0.0f;
        }
    }
    __syncthreads();

    // store: thread t covers 2 cells for its channel; 32B contiguous chunks
    const int ch = threadIdx.x >> 3;       // 0..63
    const int ci = threadIdx.x & 7;        // 0..7
    out[ch * NCELL + cbase + ci]     = R[ci][ch];
    out[ch * NCELL + cbase + ci + 8] = R[ci + 8][ch];
}

// K2 (fallback only): divide by counts + add b2 (guarded for empty cells)
__global__ void finalize_kernel(float* __restrict__ out,
                                const unsigned int* __restrict__ hist,
                                const float* __restrict__ b2)
{
    int t = blockIdx.x * 256 + threadIdx.x;
    int cell = t & (NCELL - 1);
    int ch   = t >> 16;
    float c  = (float)hist[cell];
    out[t] = out[t] / fmaxf(c, 1.0f) + ((c > 0.0f) ? b2[ch] : 0.0f);
}

extern "C" void kernel_launch(void* const* d_in, const int* in_sizes, int n_in,
                              void* d_out, int out_size, void* d_ws, size_t ws_size,
                              hipStream_t stream) {
    (void)in_sizes; (void)n_in; (void)out_size;
    const float* pos   = (const float*)d_in[0];
    const float* feats = (const float*)d_in[1];
    const float* W1    = (const float*)d_in[2];
    const float* b1    = (const float*)d_in[3];
    const float* ln_g  = (const float*)d_in[4];
    const float* ln_b  = (const float*)d_in[5];
    const float* W2    = (const float*)d_in[6];
    const float* b2    = (const float*)d_in[7];
    const int*   ax1   = (const int*)d_in[8];
    const int*   ax2   = (const int*)d_in[9];

    char* ws = (char*)d_ws;
    unsigned int* hist   = (unsigned int*)(ws + WS_HIST);
    int*          bucket = (int*)(ws + WS_BUCKET);
    _Float16*     featbf = (_Float16*)(ws + WS_FEAT);

    float* out = (float*)d_out;
    const int use_feat = (ws_size >= WS_NEED) ? 1 : 0;

    hipMemsetAsync(hist, 0, NCELL * sizeof(unsigned int), stream);
    if (!use_feat)
        hipMemsetAsync(d_out, 0, (size_t)COUT * NCELL * sizeof(float), stream);

    mlp_mfma_kernel<<<MB_BLOCKS, 512, 0, stream>>>(
        pos, feats, W1, W2, b1, ln_g, ln_b, ax1, ax2, hist,
        use_feat ? bucket : (int*)nullptr, featbf, out, use_feat);
    if (use_feat)
        reduce_kernel<<<NCELL / 16, 512, 0, stream>>>(featbf, bucket, hist, b2, out);
    else
        finalize_kernel<<<(COUT * NCELL) / 256, 256, 0, stream>>>(out, hist, b2);
}

// Round 13
// 185.129 us; speedup vs baseline: 1.0646x; 1.0646x over previous
//
#include <hip/hip_runtime.h>
#include <math.h>

// Problem constants (reference file)
#define NPTS   500000
#define CIN    16
#define COUT   64
#define GRID_W 256
#define NCELL  65536
#define BCAP   32                        // bucket capacity (P(overflow) ~ 5e-7)

// ws layout (bytes)
#define WS_HIST   0                      // 65536 u32 (256 KB)
#define WS_BUCKET 262144                 // 65536*32 u32 point-id buckets (8 MB)
#define WS_WPK    8650752                // 18432 f16 frag-packed weights (36864 B)
#define WS_FEAT   8687616                // 500000*64 f16 feature rows (64 MB)
#define WS_NEED   (WS_FEAT + (size_t)NPTS * COUT * 2)

#define MB_BLOCKS ((NPTS + 511) / 512)   // 977  (main kernel, 512 thr)

#define W_HALFS   18432                  // (28+8) frags * 64 lanes * 8 halfs
#define W1_FRAGS  28                     // 7 k-steps * 4 ch-tiles

typedef _Float16 f16x8 __attribute__((ext_vector_type(8)));
typedef _Float16 f16x2 __attribute__((ext_vector_type(2)));
typedef float    f32x4 __attribute__((ext_vector_type(4)));

__device__ __forceinline__ f16x2 pk2(float a, float b) {
    auto r = __builtin_amdgcn_cvt_pkrtz(a, b);   // v_cvt_pkrtz_f16_f32
    union { decltype(r) x; f16x2 y; } u; u.x = r;
    return u.y;
}

// raw v_sin_f32: input in REVOLUTIONS (|x| < 1 here, no range reduction needed)
__device__ __forceinline__ float vsin(float x) {
    float r;
    asm("v_sin_f32 %0, %1" : "=v"(r) : "v"(x));
    return r;
}

// raw v_exp_f32: 2^x
__device__ __forceinline__ float vexp2(float x) {
    float r;
    asm("v_exp_f32 %0, %1" : "=v"(r) : "v"(x));
    return r;
}

__device__ __forceinline__ int cell_index(float v) {
    float nf = fminf(fmaxf((v + 1.0f) * 0.5f, 0.0f), 1.0f);
    int i = (int)floorf(nf * 256.0f);
    return i > 255 ? 255 : i;
}

__device__ __forceinline__ int flat_of(const float* pos, int p, int a1, int a2) {
    float pa1 = pos[p * 3 + a1];
    float pa2 = pos[p * 3 + a2];
    return cell_index(pa1) * GRID_W + cell_index(pa2);
}

// K0: weight-pack (frag order) + hist zero-fill fused (grid 256x256 = 65536
// threads exactly covers hist; first 18432 also pack). The DEDICATED pack
// kernel is deliberate: fusing it into mlp (R12) made every block re-read
// W1/W2 with 256B-strided (uncoalesced) loads -> mlp +16us. Here wpk is
// written once; mlp re-reads it contiguously.
__global__ __launch_bounds__(256)
void pack_w_hist0_kernel(const float* __restrict__ W1,
                         const float* __restrict__ W2,
                         _Float16* __restrict__ wpk,
                         unsigned int* __restrict__ hist)
{
    int i = blockIdx.x * 256 + threadIdx.x;      // 0..65535
    if (i < W_HALFS) {
        int j = i & 7, lane = (i >> 3) & 63, f = i >> 9;
        int k  = ((f < W1_FRAGS) ? (f >> 2) : ((f - W1_FRAGS) >> 2)) * 32 + ((lane >> 4) << 3) + j;
        int ch = (f & 3) * 16 + (lane & 15);
        float v;
        if (f < W1_FRAGS) v = (k < 208) ? W1[k * 64 + ch] : 0.0f;
        else              v = W2[k * 64 + ch];
        wpk[i] = (_Float16)v;
    }
    hist[i] = 0u;
}

// K1: MFMA MLP (R5 body, 56.5us) + R9 epilogue rank assignment (returning
// atomic AFTER the wave's stores: latency overlaps other waves' MFMA).
// Rank indexes a fixed-capacity bucket directly: bucket[cell*32+lrank] = p.
__global__ __launch_bounds__(512, 4)
void mlp_mfma_kernel(const float* __restrict__ pos,
                     const float* __restrict__ feats,
                     const _Float16* __restrict__ wpk,
                     const float* __restrict__ b1,
                     const float* __restrict__ ln_g,
                     const float* __restrict__ ln_b,
                     const int*   __restrict__ ax1p,
                     const int*   __restrict__ ax2p,
                     unsigned int* __restrict__ hist,
                     int* __restrict__ bucket,
                     _Float16* __restrict__ featbuf,
                     float* __restrict__ out,
                     int use_feat)
{
    __shared__ __align__(16) _Float16 WF[W_HALFS];   // 36864 B
    __shared__ __align__(16) _Float16 PS[8 * 1024];  // 16384 B (2 KB per wave)

    // stage frag-packed weights (coalesced 16B copies)
    {
        const uint4* src = (const uint4*)wpk;
        uint4* dst = (uint4*)WF;
        for (int i = threadIdx.x; i < W_HALFS / 8; i += 512) dst[i] = src[i];
    }

    const int lane = threadIdx.x & 63;
    const int wv   = threadIdx.x >> 6;
    const int g    = lane >> 4;        // quad
    const int n    = lane & 15;        // point-within-tile (B-col / D-col)
    char* Pw = (char*)(PS + wv * 1024);            // 2048 B per wave
    const unsigned sw = (unsigned)((n & 7) << 4);  // XOR swizzle (byte, 16B unit)

    const int wbase = blockIdx.x * 512 + wv * 64;
    const int a1 = ax1p[0], a2 = ax2p[0];

    // lane-constant PE base frequency IN REVOLUTIONS: 0.25 * 2^(f0/32)
    const float base  = 0.25f * exp2f((float)((8 * g + 16) & 31) * 0.03125f);
    const float RSTEP = 1.02189714865411668f;    // 2^(1/32)

    __syncthreads();   // WF visible

    #pragma unroll 1
    for (int tp = 0; tp < 2; ++tp) {
        // ---- load 2 tiles' point data -------------------------------------
        float px[2], py[2], pz[2];
        f16x8 fH[2];
        #pragma unroll
        for (int u = 0; u < 2; ++u) {
            const int st = wbase + (tp * 2 + u) * 16 + n;
            const int p  = (st < NPTS) ? st : 0;
            px[u] = pos[3 * p + 0];
            py[u] = pos[3 * p + 1];
            pz[u] = pos[3 * p + 2];
            if (g < 2) {
                const float4* fr = (const float4*)(feats + (size_t)p * CIN + g * 8);
                float4 fa = fr[0], fb = fr[1];
                union { f16x8 v; f16x2 h[4]; } Uf;
                Uf.h[0] = pk2(fa.x, fa.y); Uf.h[1] = pk2(fa.z, fa.w);
                Uf.h[2] = pk2(fb.x, fb.y); Uf.h[3] = pk2(fb.z, fb.w);
                fH[u] = Uf.v;
            }
        }

        // ---- GEMM1: acc[u][c] = H[ch 16c+4g+r][point n], K = 224 ----------
        f32x4 acc[2][4];
        #pragma unroll
        for (int u = 0; u < 2; ++u)
            #pragma unroll
            for (int c = 0; c < 4; ++c)
                acc[u][c] = (f32x4){0.0f, 0.0f, 0.0f, 0.0f};

        #pragma unroll
        for (int s = 0; s < 7; ++s) {
            f16x8 U[2];
            const int k0 = s * 32 + g * 8;
            if (s == 0 && g < 2) {               // feats (pre-packed)
                U[0] = fH[0]; U[1] = fH[1];
            } else if (k0 >= 208) {              // zero pad (s==6, g>=2)
                union { f16x8 v; f16x2 h[4]; } Z;
                #pragma unroll
                for (int q = 0; q < 4; ++q) Z.h[q] = pk2(0.0f, 0.0f);
                U[0] = Z.v; U[1] = Z.v;
            } else {                             // PE: v_sin in revolutions
                const int   e    = k0 - 16;
                const float off  = (e & 32) ? 0.25f : 0.0f;
                const float offc = (e & 32) ? (0.25f * (1.0f - RSTEP)) : 0.0f;
                #pragma unroll
                for (int u = 0; u < 2; ++u) {
                    const float pv = (e < 64) ? px[u] : ((e < 128) ? py[u] : pz[u]);
                    float a = fmaf(pv, base, off);
                    union { f16x8 v; f16x2 h[4]; } G;
                    #pragma unroll
                    for (int q = 0; q < 4; ++q) {
                        float v0 = vsin(a); a = fmaf(a, RSTEP, offc);
                        float v1 = vsin(a); a = fmaf(a, RSTEP, offc);
                        G.h[q] = pk2(v0, v1);
                    }
                    U[u] = G.v;
                }
            }
            #pragma unroll
            for (int c = 0; c < 4; ++c) {
                f16x8 af = ((const f16x8*)WF)[(s * 4 + c) * 64 + lane];
                acc[0][c] = __builtin_amdgcn_mfma_f32_16x16x32_f16(af, U[0], acc[0][c], 0, 0, 0);
                acc[1][c] = __builtin_amdgcn_mfma_f32_16x16x32_f16(af, U[1], acc[1][c], 0, 0, 0);
            }
        }

        // ---- per tile: LN + GELU -> Pw, GEMM2, dense store ----------------
        #pragma unroll
        for (int u = 0; u < 2; ++u) {
            // LN stats (lane-local 16 + 2 shuffles)
            float s1 = 0.0f, s2 = 0.0f;
            #pragma unroll
            for (int c = 0; c < 4; ++c) {
                f32x4 b1q = *(const f32x4*)(b1 + 16 * c + 4 * g);
                #pragma unroll
                for (int r = 0; r < 4; ++r) {
                    float x = acc[u][c][r] + b1q[r];
                    acc[u][c][r] = x;
                    s1 += x; s2 += x * x;
                }
            }
            s1 += __shfl_xor(s1, 16); s2 += __shfl_xor(s2, 16);
            s1 += __shfl_xor(s1, 32); s2 += __shfl_xor(s2, 32);
            const float mu   = s1 * (1.0f / 64.0f);
            const float var  = s2 * (1.0f / 64.0f) - mu * mu;
            const float rstd = __builtin_amdgcn_rsqf(var + 1e-5f);

            // GELU via x*sigmoid(2u); exp folded to base-2: 2u*log2e in poly
            #pragma unroll
            for (int c = 0; c < 4; ++c) {
                f32x4 gq = *(const f32x4*)(ln_g + 16 * c + 4 * g);
                f32x4 bq = *(const f32x4*)(ln_b + 16 * c + 4 * g);
                float gv[4];
                #pragma unroll
                for (int r = 0; r < 4; ++r) {
                    float x  = (acc[u][c][r] - mu) * rstd * gq[r] + bq[r];
                    // 2*log2(e)*0.79788456 = 2.30211812 ; 2*log2(e)*0.03567741 = 0.10295203
                    float w  = x * (2.30211812f + 0.10295203f * x * x);
                    float e2 = vexp2(w);
                    gv[r] = x * e2 * __builtin_amdgcn_rcpf(e2 + 1.0f);
                }
                union { f16x2 h[2]; uint2 u2; } W;
                W.h[0] = pk2(gv[0], gv[1]);
                W.h[1] = pk2(gv[2], gv[3]);
                *(uint2*)(Pw + n * 128 + (((unsigned)(32 * c + 8 * g)) ^ sw)) = W.u2;
            }

            // GEMM2: acc2[c] = O[ch 16c+4g+r][point n]
            f32x4 acc2[4];
            #pragma unroll
            for (int c = 0; c < 4; ++c) acc2[c] = (f32x4){0.0f, 0.0f, 0.0f, 0.0f};
            #pragma unroll
            for (int s = 0; s < 2; ++s) {
                f16x8 bf2 = *(const f16x8*)(Pw + n * 128 + (((unsigned)(64 * s + 16 * g)) ^ sw));
                #pragma unroll
                for (int c = 0; c < 4; ++c) {
                    f16x8 af = ((const f16x8*)WF)[(W1_FRAGS + s * 4 + c) * 64 + lane];
                    acc2[c] = __builtin_amdgcn_mfma_f32_16x16x32_f16(af, bf2, acc2[c], 0, 0, 0);
                }
            }

            if (use_feat) {
                // DENSE row write straight from registers: lane (g,n) owns
                // channels 16c+4g..16c+4g+3 of point (wbase + tile*16 + n).
                const int gs = wbase + (tp * 2 + u) * 16 + n;
                if (gs < NPTS) {
                    _Float16* dstp = featbuf + (size_t)gs * COUT + 4 * g;
                    #pragma unroll
                    for (int c = 0; c < 4; ++c) {
                        union { f16x2 h[2]; uint2 u2; } W;
                        W.h[0] = pk2(acc2[c][0], acc2[c][1]);
                        W.h[1] = pk2(acc2[c][2], acc2[c][3]);
                        *(uint2*)(dstp + 16 * c) = W.u2;
                    }
                }
            } else {
                // fallback: direct fp32 atomics (correctness path, not perf)
                const int st = wbase + (tp * 2 + u) * 16 + n;
                if (st < NPTS) {
                    const int cellr = flat_of(pos, st, a1, a2);
                    #pragma unroll
                    for (int c = 0; c < 4; ++c)
                        #pragma unroll
                        for (int r = 0; r < 4; ++r)
                            unsafeAtomicAdd(&out[(size_t)(16 * c + 4 * g + r) * NCELL + cellr],
                                            acc2[c][r]);
                }
            }
        }

        // ---- rank assignment (R9 epilogue placement) -> direct bucket write.
        // Lane group g==0 handles tile u=0, g==1 handles u=1 (pos in regs).
        {
            const int st2 = wbase + (tp * 2 + (g & 1)) * 16 + n;
            if (g < 2 && st2 < NPTS) {
                const float qx = (g & 1) ? px[1] : px[0];
                const float qy = (g & 1) ? py[1] : py[0];
                const float qz = (g & 1) ? pz[1] : pz[0];
                const float pa1 = (a1 == 0) ? qx : ((a1 == 1) ? qy : qz);
                const float pa2 = (a2 == 0) ? qx : ((a2 == 1) ? qy : qz);
                const int flat = cell_index(pa1) * GRID_W + cell_index(pa2);
                const unsigned int old = atomicAdd(&hist[flat], 1u);
                if (bucket && old < BCAP) bucket[flat * BCAP + (int)old] = st2;
            }
        }
    }
}

// K2: per-cell reduce, 2 cells per wave (R12: measured ~7us better than
// 1 cell/wave — doubles gathers in flight in the latency-bound loop).
// Block = 512 thr = 8 waves = 16 cells; 4096 blocks.
__global__ __launch_bounds__(512)
void reduce_kernel(const _Float16* __restrict__ featbuf,
                   const int* __restrict__ bucket,
                   const unsigned int* __restrict__ hist,
                   const float* __restrict__ b2,
                   float* __restrict__ out)
{
    __shared__ float R[16][66];
    const int lane  = threadIdx.x & 63;
    const int wvid  = threadIdx.x >> 6;    // 0..7
    const int cbase = blockIdx.x * 16;
    const int cq    = lane & 7;            // channel octet: ch = cq*8 + j
    const int rsl   = lane >> 3;           // row slot 0..7

    const int c0 = cbase + wvid * 2;
    const int c1 = c0 + 1;
    const unsigned int cnt0 = hist[c0], cnt1 = hist[c1];
    const unsigned int cu0 = cnt0 < BCAP ? cnt0 : BCAP;
    const unsigned int cu1 = cnt1 < BCAP ? cnt1 : BCAP;
    const int bb0 = c0 * BCAP, bb1 = c1 * BCAP;

    float a0[8], a1v[8];
    #pragma unroll
    for (int j = 0; j < 8; ++j) { a0[j] = 0.0f; a1v[j] = 0.0f; }

    const unsigned int kmax = cu0 > cu1 ? cu0 : cu1;
    for (unsigned int k = 0; k < kmax; k += 8) {
        const unsigned int kk = k + (unsigned int)rsl;
        const bool ok0 = kk < cu0;
        const bool ok1 = kk < cu1;
        // clamped index keeps reads inside the bucket region; result masked
        int r0 = bucket[bb0 + (int)(ok0 ? kk : 0u)];
        int r1 = bucket[bb1 + (int)(ok1 ? kk : 0u)];
        r0 = ok0 ? r0 : 0;
        r1 = ok1 ? r1 : 0;
        union { uint4 u; f16x2 h[4]; } V0, V1;
        V0.u = *(const uint4*)(featbuf + (size_t)r0 * COUT + cq * 8);
        V1.u = *(const uint4*)(featbuf + (size_t)r1 * COUT + cq * 8);
        #pragma unroll
        for (int j = 0; j < 4; ++j) {
            a0[2 * j]      += ok0 ? (float)V0.h[j].x : 0.0f;
            a0[2 * j + 1]  += ok0 ? (float)V0.h[j].y : 0.0f;
            a1v[2 * j]     += ok1 ? (float)V1.h[j].x : 0.0f;
            a1v[2 * j + 1] += ok1 ? (float)V1.h[j].y : 0.0f;
        }
    }
    #pragma unroll
    for (int m = 8; m <= 32; m <<= 1)
        #pragma unroll
        for (int j = 0; j < 8; ++j) {
            a0[j]  += __shfl_xor(a0[j], m);
            a1v[j] += __shfl_xor(a1v[j], m);
        }

    if (rsl == 0) {
        float4 b2a = *(const float4*)(b2 + cq * 8);
        float4 b2b = *(const float4*)(b2 + cq * 8 + 4);
        const float bb[8] = {b2a.x, b2a.y, b2a.z, b2a.w, b2b.x, b2b.y, b2b.z, b2b.w};
        const float i0 = 1.0f / fmaxf((float)cnt0, 1.0f);
        const float i1 = 1.0f / fmaxf((float)cnt1, 1.0f);
        #pragma unroll
        for (int j = 0; j < 8; ++j) {
            R[wvid * 2 + 0][cq * 8 + j] = cnt0 ? (a0[j]  * i0 + bb[j]) : 0.0f;
            R[wvid * 2 + 1][cq * 8 + j] = cnt1 ? (a1v[j] * i1 + bb[j]) : 0.0f;
        }
    }
    __syncthreads();

    // store: thread t covers 2 cells for its channel; 32B contiguous chunks
    const int ch = threadIdx.x >> 3;       // 0..63
    const int ci = threadIdx.x & 7;        // 0..7
    out[ch * NCELL + cbase + ci]     = R[ci][ch];
    out[ch * NCELL + cbase + ci + 8] = R[ci + 8][ch];
}

// K3 (fallback only): divide by counts + add b2 (guarded for empty cells)
__global__ void finalize_kernel(float* __restrict__ out,
                                const unsigned int* __restrict__ hist,
                                const float* __restrict__ b2)
{
    int t = blockIdx.x * 256 + threadIdx.x;
    int cell = t & (NCELL - 1);
    int ch   = t >> 16;
    float c  = (float)hist[cell];
    out[t] = out[t] / fmaxf(c, 1.0f) + ((c > 0.0f) ? b2[ch] : 0.0f);
}

extern "C" void kernel_launch(void* const* d_in, const int* in_sizes, int n_in,
                              void* d_out, int out_size, void* d_ws, size_t ws_size,
                              hipStream_t stream) {
    (void)in_sizes; (void)n_in; (void)out_size;
    const float* pos   = (const float*)d_in[0];
    const float* feats = (const float*)d_in[1];
    const float* W1    = (const float*)d_in[2];
    const float* b1    = (const float*)d_in[3];
    const float* ln_g  = (const float*)d_in[4];
    const float* ln_b  = (const float*)d_in[5];
    const float* W2    = (const float*)d_in[6];
    const float* b2    = (const float*)d_in[7];
    const int*   ax1   = (const int*)d_in[8];
    const int*   ax2   = (const int*)d_in[9];

    char* ws = (char*)d_ws;
    unsigned int* hist   = (unsigned int*)(ws + WS_HIST);
    int*          bucket = (int*)(ws + WS_BUCKET);
    _Float16*     wpk    = (_Float16*)(ws + WS_WPK);
    _Float16*     featbf = (_Float16*)(ws + WS_FEAT);

    float* out = (float*)d_out;
    const int use_feat = (ws_size >= WS_NEED) ? 1 : 0;

    if (!use_feat)
        hipMemsetAsync(d_out, 0, (size_t)COUT * NCELL * sizeof(float), stream);

    pack_w_hist0_kernel<<<256, 256, 0, stream>>>(W1, W2, wpk, hist);
    mlp_mfma_kernel<<<MB_BLOCKS, 512, 0, stream>>>(
        pos, feats, wpk, b1, ln_g, ln_b, ax1, ax2, hist,
        use_feat ? bucket : (int*)nullptr, featbf, out, use_feat);
    if (use_feat)
        reduce_kernel<<<NCELL / 16, 512, 0, stream>>>(featbf, bucket, hist, b2, out);
    else
        finalize_kernel<<<(COUT * NCELL) / 256, 256, 0, stream>>>(out, hist, b2);
}